// Round 4
// baseline (454.076 us; speedup 1.0000x reference)
//
#include <hip/hip_runtime.h>
#include <hip/hip_bf16.h>

// Problem constants (from reference)
#define BB   32
#define CC   256
#define CTXN 512
#define HWN  4096                    // 64*64
#define N4   ((long)(BB * CC * HWN) / 4)   // float4 elements = 8,388,608 = 2^23

typedef float vfloat4 __attribute__((ext_vector_type(4)));

// ---------------------------------------------------------------------------
// Kernel A: per-batch projection (unchanged, ~4 us, L2-resident weights).
// ---------------------------------------------------------------------------
__global__ __launch_bounds__(256)
void ca_proj_kernel(const float* __restrict__ context,
                    const float* __restrict__ Wkv,
                    const float* __restrict__ bkv,
                    const float* __restrict__ Wout,
                    const float* __restrict__ bout,
                    float* __restrict__ y)
{
    __shared__ float ctx_sh[CTXN];
    __shared__ float v_sh[CC];

    const int b = blockIdx.x;
    const int t = threadIdx.x;

    ctx_sh[t]       = context[b * CTXN + t];
    ctx_sh[t + 256] = context[b * CTXN + t + 256];
    __syncthreads();

    {
        const float4* w4 = reinterpret_cast<const float4*>(Wkv + (size_t)(CC + t) * CTXN);
        const float4* c4 = reinterpret_cast<const float4*>(ctx_sh);
        float acc = bkv[CC + t];
        #pragma unroll 8
        for (int i = 0; i < CTXN / 4; ++i) {
            float4 w = w4[i];
            float4 c = c4[i];
            acc += w.x * c.x + w.y * c.y + w.z * c.z + w.w * c.w;
        }
        v_sh[t] = acc;
    }
    __syncthreads();

    {
        const float4* w4 = reinterpret_cast<const float4*>(Wout + (size_t)t * CC);
        const float4* v4 = reinterpret_cast<const float4*>(v_sh);
        float acc = bout[t];
        #pragma unroll 8
        for (int i = 0; i < CC / 4; ++i) {
            float4 w = w4[i];
            float4 v = v4[i];
            acc += w.x * v.x + w.y * v.y + w.z * v.z + w.w * v.w;
        }
        y[b * CC + t] = acc;
    }
}

// ---------------------------------------------------------------------------
// Kernel B: out = x + y[plane]; stores with nt+sc1 (L2/L3 no-alloc hint).
// ---------------------------------------------------------------------------
__global__ __launch_bounds__(256)
void ca_add_kernel(const float* __restrict__ x,
                   const float* __restrict__ y,
                   float* __restrict__ out)
{
    const int g     = blockIdx.x * 256 + threadIdx.x;
    const int plane = g >> 7;
    const int lane  = g & 127;
    const long base = (long)plane * 1024 + lane;

    const float yv = y[plane];

    const vfloat4* __restrict__ x4 = reinterpret_cast<const vfloat4*>(x);
    vfloat4*       __restrict__ o4 = reinterpret_cast<vfloat4*>(out);

    vfloat4 r[8];
    #pragma unroll
    for (int j = 0; j < 8; ++j)
        r[j] = x4[base + (long)j * 128];

    #pragma unroll
    for (int j = 0; j < 8; ++j) {
        vfloat4 v = r[j];
        v.x += yv; v.y += yv; v.z += yv; v.w += yv;
        vfloat4* p = &o4[base + (long)j * 128];
        asm volatile("global_store_dwordx4 %0, %1, off nt sc1"
                     :: "v"(p), "v"(v) : "memory");
    }
}

// ---------------------------------------------------------------------------
// PROBE P0: plain float4 copy x -> dst, 2 full passes. In-context copy ceiling.
// ---------------------------------------------------------------------------
__global__ __launch_bounds__(256)
void probe_copy_plain(const float* __restrict__ x, float* __restrict__ dst)
{
    const vfloat4* x4 = reinterpret_cast<const vfloat4*>(x);
    vfloat4*       d4 = reinterpret_cast<vfloat4*>(dst);
    const long t      = (long)blockIdx.x * 256 + threadIdx.x;
    const long stride = (long)gridDim.x * 256;

    for (int p = 0; p < 2; ++p) {
        for (long i = t; i < N4; i += stride)
            d4[i] = x4[i];
        asm volatile("" ::: "memory");   // keep passes distinct (no cross-pass DSE/CSE)
    }
}

// ---------------------------------------------------------------------------
// PROBE P1: copy with nt+sc1 stores, 4 full passes. If the bypass keeps dst
// out of L3, passes 2..4 read fully L3-resident x -> much faster per pass.
// ---------------------------------------------------------------------------
__global__ __launch_bounds__(256)
void probe_copy_bypass(const float* __restrict__ x, float* __restrict__ dst)
{
    const vfloat4* x4 = reinterpret_cast<const vfloat4*>(x);
    vfloat4*       d4 = reinterpret_cast<vfloat4*>(dst);
    const long t      = (long)blockIdx.x * 256 + threadIdx.x;
    const long stride = (long)gridDim.x * 256;

    for (int p = 0; p < 4; ++p) {
        for (long i = t; i < N4; i += stride) {
            vfloat4 v = x4[i];
            vfloat4* pd = &d4[i];
            asm volatile("global_store_dwordx4 %0, %1, off nt sc1"
                         :: "v"(pd), "v"(v) : "memory");
        }
        asm volatile("" ::: "memory");
    }
}

// ---------------------------------------------------------------------------
// PROBE P3: read-only sum of x, 8 full passes. Pure read BW; passes 2..8
// measure L3-read bandwidth (x is the only 134 MB touched).
// ---------------------------------------------------------------------------
__global__ __launch_bounds__(256)
void probe_read_sum(const float* __restrict__ x, float* __restrict__ dst)
{
    const vfloat4* x4 = reinterpret_cast<const vfloat4*>(x);
    const long t      = (long)blockIdx.x * 256 + threadIdx.x;
    const long stride = (long)gridDim.x * 256;

    vfloat4 acc = {0.f, 0.f, 0.f, 0.f};
    for (int p = 0; p < 8; ++p) {
        for (long i = t; i < N4; i += stride) {
            vfloat4 v = x4[i];
            acc.x += v.x; acc.y += v.y; acc.z += v.z; acc.w += v.w;
        }
        asm volatile("" ::: "memory");
    }
    reinterpret_cast<vfloat4*>(dst)[t] = acc;   // keep loads live
}

extern "C" void kernel_launch(void* const* d_in, const int* in_sizes, int n_in,
                              void* d_out, int out_size, void* d_ws, size_t ws_size,
                              hipStream_t stream)
{
    // setup_inputs() order:
    // 0:x 1:context 2:gn_w 3:gn_b 4:Wq 5:bq 6:Wkv 7:bkv 8:Wout 9:bout
    const float* x       = (const float*)d_in[0];
    const float* context = (const float*)d_in[1];
    const float* Wkv     = (const float*)d_in[6];
    const float* bkv     = (const float*)d_in[7];
    const float* Wout    = (const float*)d_in[8];
    const float* bout    = (const float*)d_in[9];
    float*       out     = (float*)d_out;
    float*       y       = (float*)d_ws;   // 32*256*4 = 32 KB at ws offset 0

    ca_proj_kernel<<<BB, 256, 0, stream>>>(context, Wkv, bkv, Wout, bout, y);
    ca_add_kernel<<<4096, 256, 0, stream>>>(x, y, out);

    // -------- diagnostic probes (deterministic; write only to d_ws) --------
    if (ws_size >= ((size_t)400 << 20)) {
        float* cpy_dst = (float*)((char*)d_ws + ((size_t)192 << 20)); // 134 MB region
        float* sum_dst = (float*)((char*)d_ws + ((size_t)384 << 20)); // 8 MB region
        probe_copy_plain <<<2048, 256, 0, stream>>>(x, cpy_dst);
        probe_copy_bypass<<<2048, 256, 0, stream>>>(x, cpy_dst);
        probe_read_sum   <<<2048, 256, 0, stream>>>(x, sum_dst);
    }
}

// Round 6
// 70.143 us; speedup vs baseline: 6.4736x; 6.4736x over previous
//
#include <hip/hip_runtime.h>
#include <hip/hip_bf16.h>

// Problem constants (from reference)
#define BB   32
#define CC   256
#define CTXN 512
#define HWN  4096
#define N4   ((long)8388608)   // total float4 elements (32*256*64*64/4)

typedef float vfloat4 __attribute__((ext_vector_type(4)));

// ---------------------------------------------------------------------------
// Kernel A: per-batch projection (EXACT R1 version — validated in rounds 1-3).
//   v[c] = bkv[C+c] + context[b,:] . Wkv[C+c,:]
//   y[b,o] = bout[o] + Wout[o,:] . v[:]
// One block per batch (32 blocks, 256 threads). L2-resident weights.
// ---------------------------------------------------------------------------
__global__ __launch_bounds__(256)
void ca_proj_kernel(const float* __restrict__ context,
                    const float* __restrict__ Wkv,
                    const float* __restrict__ bkv,
                    const float* __restrict__ Wout,
                    const float* __restrict__ bout,
                    float* __restrict__ y)
{
    __shared__ float ctx_sh[CTXN];
    __shared__ float v_sh[CC];

    const int b = blockIdx.x;
    const int t = threadIdx.x;   // 0..255

    ctx_sh[t]       = context[b * CTXN + t];
    ctx_sh[t + 256] = context[b * CTXN + t + 256];
    __syncthreads();

    {
        const float4* w4 = reinterpret_cast<const float4*>(Wkv + (size_t)(CC + t) * CTXN);
        const float4* c4 = reinterpret_cast<const float4*>(ctx_sh);
        float acc = bkv[CC + t];
        #pragma unroll 8
        for (int i = 0; i < CTXN / 4; ++i) {
            float4 w = w4[i];
            float4 c = c4[i];
            acc += w.x * c.x + w.y * c.y + w.z * c.z + w.w * c.w;
        }
        v_sh[t] = acc;
    }
    __syncthreads();

    {
        const float4* w4 = reinterpret_cast<const float4*>(Wout + (size_t)t * CC);
        const float4* v4 = reinterpret_cast<const float4*>(v_sh);
        float acc = bout[t];
        #pragma unroll 8
        for (int i = 0; i < CC / 4; ++i) {
            float4 w = w4[i];
            float4 v = v4[i];
            acc += w.x * v.x + w.y * v.y + w.z * v.z + w.w * v.w;
        }
        y[b * CC + t] = acc;
    }
}

// ---------------------------------------------------------------------------
// Kernel B: out = x + y[plane].  EXACT probe_copy_bypass structure (40.1
// us/pass measured in R4) with the broadcast add folded in:
//   2048 blocks x 256 threads, 1-deep grid-stride, nt+sc1 stores
//   (asm form correctness-validated in R4's ca_add).
// y is 32 KB -> L1/L2-resident; y addresses are loop-independent, so loads
// pipeline despite the per-store memory clobber.
// ---------------------------------------------------------------------------
__global__ __launch_bounds__(256)
void ca_add_kernel(const float* __restrict__ x,
                   const float* __restrict__ y,
                   float* __restrict__ out)
{
    const vfloat4* __restrict__ x4 = reinterpret_cast<const vfloat4*>(x);
    vfloat4*       __restrict__ o4 = reinterpret_cast<vfloat4*>(out);

    const long t      = (long)blockIdx.x * 256 + threadIdx.x;
    const long stride = (long)2048 * 256;

    for (long i = t; i < N4; i += stride) {
        vfloat4 v = x4[i];
        const float yv = y[i >> 10];     // plane id = f4_index >> 10
        v.x += yv; v.y += yv; v.z += yv; v.w += yv;
        vfloat4* pd = &o4[i];
        asm volatile("global_store_dwordx4 %0, %1, off nt sc1"
                     :: "v"(pd), "v"(v) : "memory");
    }
}

extern "C" void kernel_launch(void* const* d_in, const int* in_sizes, int n_in,
                              void* d_out, int out_size, void* d_ws, size_t ws_size,
                              hipStream_t stream)
{
    // setup_inputs() order:
    // 0:x 1:context 2:gn_w 3:gn_b 4:Wq 5:bq 6:Wkv 7:bkv 8:Wout 9:bout
    const float* x       = (const float*)d_in[0];
    const float* context = (const float*)d_in[1];
    const float* Wkv     = (const float*)d_in[6];
    const float* bkv     = (const float*)d_in[7];
    const float* Wout    = (const float*)d_in[8];
    const float* bout    = (const float*)d_in[9];
    float*       out     = (float*)d_out;
    float*       y       = (float*)d_ws;   // 32*256*4 = 32 KB

    ca_proj_kernel<<<BB,   256, 0, stream>>>(context, Wkv, bkv, Wout, bout, y);
    ca_add_kernel <<<2048, 256, 0, stream>>>(x, y, out);
}

// Round 7
// 67.662 us; speedup vs baseline: 6.7109x; 1.0367x over previous
//
#include <hip/hip_runtime.h>
#include <hip/hip_bf16.h>

// Problem constants (from reference)
#define BB   32
#define CC   256
#define CTXN 512
#define HWN  4096
#define NPLANES (BB * CC)          // 8192 (b,c) planes, 1024 float4 each

typedef float vfloat4 __attribute__((ext_vector_type(4)));

// ---------------------------------------------------------------------------
// Kernel A: per-batch projection (EXACT R1 version — validated rounds 1-3,6).
//   v[c] = bkv[C+c] + context[b,:] . Wkv[C+c,:]
//   y[b,o] = bout[o] + Wout[o,:] . v[:]
// ---------------------------------------------------------------------------
__global__ __launch_bounds__(256)
void ca_proj_kernel(const float* __restrict__ context,
                    const float* __restrict__ Wkv,
                    const float* __restrict__ bkv,
                    const float* __restrict__ Wout,
                    const float* __restrict__ bout,
                    float* __restrict__ y)
{
    __shared__ float ctx_sh[CTXN];
    __shared__ float v_sh[CC];

    const int b = blockIdx.x;
    const int t = threadIdx.x;   // 0..255

    ctx_sh[t]       = context[b * CTXN + t];
    ctx_sh[t + 256] = context[b * CTXN + t + 256];
    __syncthreads();

    {
        const float4* w4 = reinterpret_cast<const float4*>(Wkv + (size_t)(CC + t) * CTXN);
        const float4* c4 = reinterpret_cast<const float4*>(ctx_sh);
        float acc = bkv[CC + t];
        #pragma unroll 8
        for (int i = 0; i < CTXN / 4; ++i) {
            float4 w = w4[i];
            float4 c = c4[i];
            acc += w.x * c.x + w.y * c.y + w.z * c.z + w.w * c.w;
        }
        v_sh[t] = acc;
    }
    __syncthreads();

    {
        const float4* w4 = reinterpret_cast<const float4*>(Wout + (size_t)t * CC);
        const float4* v4 = reinterpret_cast<const float4*>(v_sh);
        float acc = bout[t];
        #pragma unroll 8
        for (int i = 0; i < CC / 4; ++i) {
            float4 w = w4[i];
            float4 v = v4[i];
            acc += w.x * v.x + w.y * v.y + w.z * v.z + w.w * v.w;
        }
        y[b * CC + t] = acc;
    }
}

// ---------------------------------------------------------------------------
// Kernel B: out = x + y[plane].  One block per plane (8192 blocks x 256 thr):
//   - y[blockIdx.x] is wave-uniform -> scalar s_load, zero VMEM in data path
//   - each thread: exactly 4 float4, fully unrolled (4-deep MLP)
//   - nontemporal stores (R3-validated best form)
//   - no loop, no tail, perfect coalescing (1 KB/wave/instr)
// ---------------------------------------------------------------------------
__global__ __launch_bounds__(256)
void ca_add_kernel(const float* __restrict__ x,
                   const float* __restrict__ y,
                   float* __restrict__ out)
{
    const int  p    = blockIdx.x;                       // plane id 0..8191
    const long base = (long)p * 1024 + threadIdx.x;     // float4 index

    const float yv = y[p];                              // uniform -> s_load

    const vfloat4* __restrict__ x4 = reinterpret_cast<const vfloat4*>(x);
    vfloat4*       __restrict__ o4 = reinterpret_cast<vfloat4*>(out);

    vfloat4 r0 = x4[base];
    vfloat4 r1 = x4[base + 256];
    vfloat4 r2 = x4[base + 512];
    vfloat4 r3 = x4[base + 768];

    r0.x += yv; r0.y += yv; r0.z += yv; r0.w += yv;
    r1.x += yv; r1.y += yv; r1.z += yv; r1.w += yv;
    r2.x += yv; r2.y += yv; r2.z += yv; r2.w += yv;
    r3.x += yv; r3.y += yv; r3.z += yv; r3.w += yv;

    __builtin_nontemporal_store(r0, &o4[base]);
    __builtin_nontemporal_store(r1, &o4[base + 256]);
    __builtin_nontemporal_store(r2, &o4[base + 512]);
    __builtin_nontemporal_store(r3, &o4[base + 768]);
}

extern "C" void kernel_launch(void* const* d_in, const int* in_sizes, int n_in,
                              void* d_out, int out_size, void* d_ws, size_t ws_size,
                              hipStream_t stream)
{
    // setup_inputs() order:
    // 0:x 1:context 2:gn_w 3:gn_b 4:Wq 5:bq 6:Wkv 7:bkv 8:Wout 9:bout
    const float* x       = (const float*)d_in[0];
    const float* context = (const float*)d_in[1];
    const float* Wkv     = (const float*)d_in[6];
    const float* bkv     = (const float*)d_in[7];
    const float* Wout    = (const float*)d_in[8];
    const float* bout    = (const float*)d_in[9];
    float*       out     = (float*)d_out;
    float*       y       = (float*)d_ws;   // 32*256*4 = 32 KB

    ca_proj_kernel<<<BB,      256, 0, stream>>>(context, Wkv, bkv, Wout, bout, y);
    ca_add_kernel <<<NPLANES, 256, 0, stream>>>(x, y, out);
}

// Round 8
// 58.494 us; speedup vs baseline: 7.7628x; 1.1567x over previous
//
#include <hip/hip_runtime.h>
#include <hip/hip_bf16.h>

// Problem constants (from reference)
#define BB   32
#define CC   256
#define CTXN 512
#define HWN  4096
#define NPLANES (BB * CC)          // 8192 (b,c) planes, 1024 float4 each

typedef float vfloat4 __attribute__((ext_vector_type(4)));

// ---------------------------------------------------------------------------
// Kernel A1: v[b][c] = bkv[C+c] + dot(context[b,:], Wkv[C+c,:])   (len 512)
// 8192 outputs x 4 threads each = 32768 threads = 128 blocks.
// Thread q of group o reads 128 floats (32 f4) at offset q*128; reduce via
// shfl_xor(1)+shfl_xor(2) (groups of 4 are lane-aligned within a wave).
// ---------------------------------------------------------------------------
__global__ __launch_bounds__(256)
void ca_v_kernel(const float* __restrict__ context,
                 const float* __restrict__ Wkv,
                 const float* __restrict__ bkv,
                 float* __restrict__ v)
{
    const int gid = blockIdx.x * 256 + threadIdx.x;   // 0..32767
    const int o   = gid >> 2;                         // 0..8191
    const int q   = gid & 3;
    const int b   = o >> 8;
    const int c   = o & 255;

    const vfloat4* w4 = reinterpret_cast<const vfloat4*>(
        Wkv + (size_t)(CC + c) * CTXN + q * 128);
    const vfloat4* c4 = reinterpret_cast<const vfloat4*>(
        context + (size_t)b * CTXN + q * 128);

    float acc = 0.f;
    #pragma unroll 8
    for (int i = 0; i < 32; ++i) {
        vfloat4 w = w4[i], x = c4[i];
        acc += w.x * x.x + w.y * x.y + w.z * x.z + w.w * x.w;
    }
    acc += __shfl_xor(acc, 1);
    acc += __shfl_xor(acc, 2);
    if (q == 0) v[o] = acc + bkv[CC + c];
}

// ---------------------------------------------------------------------------
// Kernel A2: y[b][o] = bout[o] + dot(v[b,:], Wout[o,:])   (len 256)
// Same structure: 4 threads/output, 64 floats (16 f4) each. 128 blocks.
// ---------------------------------------------------------------------------
__global__ __launch_bounds__(256)
void ca_y_kernel(const float* __restrict__ v,
                 const float* __restrict__ Wout,
                 const float* __restrict__ bout,
                 float* __restrict__ y)
{
    const int gid = blockIdx.x * 256 + threadIdx.x;   // 0..32767
    const int o   = gid >> 2;                         // 0..8191
    const int q   = gid & 3;
    const int b   = o >> 8;
    const int oc  = o & 255;

    const vfloat4* w4 = reinterpret_cast<const vfloat4*>(
        Wout + (size_t)oc * CC + q * 64);
    const vfloat4* v4 = reinterpret_cast<const vfloat4*>(
        v + (size_t)b * CC + q * 64);

    float acc = 0.f;
    #pragma unroll 8
    for (int i = 0; i < 16; ++i) {
        vfloat4 w = w4[i], x = v4[i];
        acc += w.x * x.x + w.y * x.y + w.z * x.z + w.w * x.w;
    }
    acc += __shfl_xor(acc, 1);
    acc += __shfl_xor(acc, 2);
    if (q == 0) y[o] = acc + bout[oc];
}

// ---------------------------------------------------------------------------
// Kernel B: out = x + y[plane].  EXACT R7 version (validated):
// one block per plane, y via scalar s_load, 4 f4/thread fully unrolled,
// builtin nontemporal stores. No loop, no tail, perfect coalescing.
// ---------------------------------------------------------------------------
__global__ __launch_bounds__(256)
void ca_add_kernel(const float* __restrict__ x,
                   const float* __restrict__ y,
                   float* __restrict__ out)
{
    const int  p    = blockIdx.x;                       // plane id 0..8191
    const long base = (long)p * 1024 + threadIdx.x;     // float4 index

    const float yv = y[p];                              // uniform -> s_load

    const vfloat4* __restrict__ x4 = reinterpret_cast<const vfloat4*>(x);
    vfloat4*       __restrict__ o4 = reinterpret_cast<vfloat4*>(out);

    vfloat4 r0 = x4[base];
    vfloat4 r1 = x4[base + 256];
    vfloat4 r2 = x4[base + 512];
    vfloat4 r3 = x4[base + 768];

    r0.x += yv; r0.y += yv; r0.z += yv; r0.w += yv;
    r1.x += yv; r1.y += yv; r1.z += yv; r1.w += yv;
    r2.x += yv; r2.y += yv; r2.z += yv; r2.w += yv;
    r3.x += yv; r3.y += yv; r3.z += yv; r3.w += yv;

    __builtin_nontemporal_store(r0, &o4[base]);
    __builtin_nontemporal_store(r1, &o4[base + 256]);
    __builtin_nontemporal_store(r2, &o4[base + 512]);
    __builtin_nontemporal_store(r3, &o4[base + 768]);
}

extern "C" void kernel_launch(void* const* d_in, const int* in_sizes, int n_in,
                              void* d_out, int out_size, void* d_ws, size_t ws_size,
                              hipStream_t stream)
{
    // setup_inputs() order:
    // 0:x 1:context 2:gn_w 3:gn_b 4:Wq 5:bq 6:Wkv 7:bkv 8:Wout 9:bout
    const float* x       = (const float*)d_in[0];
    const float* context = (const float*)d_in[1];
    const float* Wkv     = (const float*)d_in[6];
    const float* bkv     = (const float*)d_in[7];
    const float* Wout    = (const float*)d_in[8];
    const float* bout    = (const float*)d_in[9];
    float*       out     = (float*)d_out;

    float* y = (float*)d_ws;                          // 32 KB
    float* v = (float*)((char*)d_ws + (64 << 10));    // 32 KB at +64 KB

    ca_v_kernel  <<<128,     256, 0, stream>>>(context, Wkv, bkv, v);
    ca_y_kernel  <<<128,     256, 0, stream>>>(v, Wout, bout, y);
    ca_add_kernel<<<NPLANES, 256, 0, stream>>>(x, y, out);
}

// Round 9
// 53.112 us; speedup vs baseline: 8.5494x; 1.1013x over previous
//
#include <hip/hip_runtime.h>
#include <hip/hip_bf16.h>

// Problem constants (from reference)
#define BB   32
#define CC   256
#define CTXN 512
#define HWN  4096
#define NPLANES (BB * CC)          // 8192 (b,c) planes, 1024 float4 each

typedef float vfloat4 __attribute__((ext_vector_type(4)));

// ---------------------------------------------------------------------------
// Kernel A: v[b][c] = bkv[C+c] + dot(context[b,:], Wkv[C+c,:])   (len 512)
// 8192 outputs x 4 threads each = 32768 threads = 128 blocks (validated R8).
// ---------------------------------------------------------------------------
__global__ __launch_bounds__(256)
void ca_v_kernel(const float* __restrict__ context,
                 const float* __restrict__ Wkv,
                 const float* __restrict__ bkv,
                 float* __restrict__ v)
{
    const int gid = blockIdx.x * 256 + threadIdx.x;   // 0..32767
    const int o   = gid >> 2;                         // 0..8191
    const int q   = gid & 3;
    const int b   = o >> 8;
    const int c   = o & 255;

    const vfloat4* w4 = reinterpret_cast<const vfloat4*>(
        Wkv + (size_t)(CC + c) * CTXN + q * 128);
    const vfloat4* c4 = reinterpret_cast<const vfloat4*>(
        context + (size_t)b * CTXN + q * 128);

    float acc = 0.f;
    #pragma unroll 8
    for (int i = 0; i < 32; ++i) {
        vfloat4 w = w4[i], x = c4[i];
        acc += w.x * x.x + w.y * x.y + w.z * x.z + w.w * x.w;
    }
    acc += __shfl_xor(acc, 1);
    acc += __shfl_xor(acc, 2);
    if (q == 0) v[o] = acc + bkv[CC + c];
}

// ---------------------------------------------------------------------------
// Kernel B (fused): out[p] = x[p] + y[p], with y[p] computed in-block:
//   p = (b,c);  y[p] = bout[c] + dot(v[b,:], Wout[c,:])   (len 256)
// Order: issue the 4 x-loads first (in flight), then 1 MAC/thread +
// shfl/LDS block-reduce (hidden under VMEM latency), then add + nt-store.
// Add structure = EXACT R7/R8 validated form (8192 blocks, 4 f4/thread).
// ---------------------------------------------------------------------------
__global__ __launch_bounds__(256)
void ca_add_kernel(const float* __restrict__ x,
                   const float* __restrict__ v,
                   const float* __restrict__ Wout,
                   const float* __restrict__ bout,
                   float* __restrict__ out)
{
    const int  p    = blockIdx.x;                       // plane id 0..8191
    const int  b    = p >> 8;
    const int  c    = p & 255;
    const int  t    = threadIdx.x;
    const long base = (long)p * 1024 + t;               // float4 index

    const vfloat4* __restrict__ x4 = reinterpret_cast<const vfloat4*>(x);
    vfloat4*       __restrict__ o4 = reinterpret_cast<vfloat4*>(out);

    // issue the streaming loads first — everything below hides under them
    vfloat4 r0 = x4[base];
    vfloat4 r1 = x4[base + 256];
    vfloat4 r2 = x4[base + 512];
    vfloat4 r3 = x4[base + 768];

    // per-block y: 1 MAC/thread over v[b,:] * Wout[c,:], block-reduce
    __shared__ float red[4];
    float part = v[b * CC + t] * Wout[(size_t)c * CC + t];
    part += __shfl_xor(part, 1);
    part += __shfl_xor(part, 2);
    part += __shfl_xor(part, 4);
    part += __shfl_xor(part, 8);
    part += __shfl_xor(part, 16);
    part += __shfl_xor(part, 32);
    if ((t & 63) == 0) red[t >> 6] = part;
    __syncthreads();
    const float yv = bout[c] + red[0] + red[1] + red[2] + red[3];

    r0.x += yv; r0.y += yv; r0.z += yv; r0.w += yv;
    r1.x += yv; r1.y += yv; r1.z += yv; r1.w += yv;
    r2.x += yv; r2.y += yv; r2.z += yv; r2.w += yv;
    r3.x += yv; r3.y += yv; r3.z += yv; r3.w += yv;

    __builtin_nontemporal_store(r0, &o4[base]);
    __builtin_nontemporal_store(r1, &o4[base + 256]);
    __builtin_nontemporal_store(r2, &o4[base + 512]);
    __builtin_nontemporal_store(r3, &o4[base + 768]);
}

extern "C" void kernel_launch(void* const* d_in, const int* in_sizes, int n_in,
                              void* d_out, int out_size, void* d_ws, size_t ws_size,
                              hipStream_t stream)
{
    // setup_inputs() order:
    // 0:x 1:context 2:gn_w 3:gn_b 4:Wq 5:bq 6:Wkv 7:bkv 8:Wout 9:bout
    const float* x       = (const float*)d_in[0];
    const float* context = (const float*)d_in[1];
    const float* Wkv     = (const float*)d_in[6];
    const float* bkv     = (const float*)d_in[7];
    const float* Wout    = (const float*)d_in[8];
    const float* bout    = (const float*)d_in[9];
    float*       out     = (float*)d_out;

    float* v = (float*)d_ws;                          // 32 KB scratch

    ca_v_kernel  <<<128,     256, 0, stream>>>(context, Wkv, bkv, v);
    ca_add_kernel<<<NPLANES, 256, 0, stream>>>(x, v, Wout, bout, out);
}

// Round 10
// 52.684 us; speedup vs baseline: 8.6189x; 1.0081x over previous
//
#include <hip/hip_runtime.h>
#include <hip/hip_bf16.h>

// Problem constants (from reference)
#define BB   32
#define CC   256
#define CTXN 512
#define HWN  4096
#define NPLANES (BB * CC)          // 8192 (b,c) planes, 1024 float4 each

typedef float vfloat4 __attribute__((ext_vector_type(4)));

// ---------------------------------------------------------------------------
// Kernel A: v[b][c] = bkv[C+c] + dot(context[b,:], Wkv[C+c,:])   (len 512)
// 8192 outputs x 4 threads each = 128 blocks (validated R8/R9).
// ---------------------------------------------------------------------------
__global__ __launch_bounds__(256)
void ca_v_kernel(const float* __restrict__ context,
                 const float* __restrict__ Wkv,
                 const float* __restrict__ bkv,
                 float* __restrict__ v)
{
    const int gid = blockIdx.x * 256 + threadIdx.x;   // 0..32767
    const int o   = gid >> 2;                         // 0..8191
    const int q   = gid & 3;
    const int b   = o >> 8;
    const int c   = o & 255;

    const vfloat4* w4 = reinterpret_cast<const vfloat4*>(
        Wkv + (size_t)(CC + c) * CTXN + q * 128);
    const vfloat4* c4 = reinterpret_cast<const vfloat4*>(
        context + (size_t)b * CTXN + q * 128);

    float acc = 0.f;
    #pragma unroll 8
    for (int i = 0; i < 32; ++i) {
        vfloat4 w = w4[i], xx = c4[i];
        acc += w.x * xx.x + w.y * xx.y + w.z * xx.z + w.w * xx.w;
    }
    acc += __shfl_xor(acc, 1);
    acc += __shfl_xor(acc, 2);
    if (q == 0) v[o] = acc + bkv[CC + c];
}

// ---------------------------------------------------------------------------
// Kernel B (fused, 4-plane pipelined): block g owns planes 4g..4g+3
// (same b, consecutive c). Issue order creates a descending vmcnt ladder:
//   1) 5 small L2-resident y-input loads (v row + 4 Wout rows)
//   2) 16 x-loads back-to-back (deep per-thread MLP, the probe's regime)
//   3) 4 wave-local shfl reduces (NO barrier -> no vmcnt(0) drain)
//   4) per-plane add + NT store, each waiting only on its own 4 loads
// ---------------------------------------------------------------------------
__global__ __launch_bounds__(256)
void ca_add_kernel(const float* __restrict__ x,
                   const float* __restrict__ v,
                   const float* __restrict__ Wout,
                   const float* __restrict__ bout,
                   float* __restrict__ out)
{
    const int g  = blockIdx.x;          // 0..2047
    const int p0 = g << 2;              // planes p0..p0+3
    const int b  = p0 >> 8;
    const int c0 = p0 & 255;            // c0..c0+3 (4-aligned, same b)
    const int t  = threadIdx.x;
    const int l  = t & 63;

    const vfloat4* __restrict__ x4 = reinterpret_cast<const vfloat4*>(x);
    vfloat4*       __restrict__ o4 = reinterpret_cast<vfloat4*>(out);

    // 1) y-inputs first (L2-resident, return fast)
    const vfloat4 vv = reinterpret_cast<const vfloat4*>(v + b * CC)[l];
    const vfloat4 w0 = reinterpret_cast<const vfloat4*>(Wout + (size_t)(c0 + 0) * CC)[l];
    const vfloat4 w1 = reinterpret_cast<const vfloat4*>(Wout + (size_t)(c0 + 1) * CC)[l];
    const vfloat4 w2 = reinterpret_cast<const vfloat4*>(Wout + (size_t)(c0 + 2) * CC)[l];
    const vfloat4 w3 = reinterpret_cast<const vfloat4*>(Wout + (size_t)(c0 + 3) * CC)[l];

    // 2) 16 streaming x-loads, all in flight
    const long base = (long)p0 * 1024 + t;
    vfloat4 r[4][4];
    #pragma unroll
    for (int j = 0; j < 4; ++j)
        #pragma unroll
        for (int k = 0; k < 4; ++k)
            r[j][k] = x4[base + j * 1024 + k * 256];

    // 3) wave-local dot reduces (hidden under x-load latency)
    float pr[4];
    pr[0] = vv.x * w0.x + vv.y * w0.y + vv.z * w0.z + vv.w * w0.w;
    pr[1] = vv.x * w1.x + vv.y * w1.y + vv.z * w1.z + vv.w * w1.w;
    pr[2] = vv.x * w2.x + vv.y * w2.y + vv.z * w2.z + vv.w * w2.w;
    pr[3] = vv.x * w3.x + vv.y * w3.y + vv.z * w3.z + vv.w * w3.w;
    #pragma unroll
    for (int off = 1; off < 64; off <<= 1) {
        pr[0] += __shfl_xor(pr[0], off);
        pr[1] += __shfl_xor(pr[1], off);
        pr[2] += __shfl_xor(pr[2], off);
        pr[3] += __shfl_xor(pr[3], off);
    }
    float yv[4];
    #pragma unroll
    for (int j = 0; j < 4; ++j)
        yv[j] = pr[j] + bout[c0 + j];

    // 4) per-plane add + NT store (vmcnt ladder 12/8/4/0)
    #pragma unroll
    for (int j = 0; j < 4; ++j) {
        const float yj = yv[j];
        #pragma unroll
        for (int k = 0; k < 4; ++k) {
            vfloat4 val = r[j][k];
            val.x += yj; val.y += yj; val.z += yj; val.w += yj;
            __builtin_nontemporal_store(val, &o4[base + j * 1024 + k * 256]);
        }
    }
}

extern "C" void kernel_launch(void* const* d_in, const int* in_sizes, int n_in,
                              void* d_out, int out_size, void* d_ws, size_t ws_size,
                              hipStream_t stream)
{
    // setup_inputs() order:
    // 0:x 1:context 2:gn_w 3:gn_b 4:Wq 5:bq 6:Wkv 7:bkv 8:Wout 9:bout
    const float* x       = (const float*)d_in[0];
    const float* context = (const float*)d_in[1];
    const float* Wkv     = (const float*)d_in[6];
    const float* bkv     = (const float*)d_in[7];
    const float* Wout    = (const float*)d_in[8];
    const float* bout    = (const float*)d_in[9];
    float*       out     = (float*)d_out;

    float* v = (float*)d_ws;                          // 32 KB scratch

    ca_v_kernel  <<<128,          256, 0, stream>>>(context, Wkv, bkv, v);
    ca_add_kernel<<<NPLANES / 4,  256, 0, stream>>>(x, v, Wout, bout, out);
}